// Round 8
// baseline (214.010 us; speedup 1.0000x reference)
//
#include <hip/hip_runtime.h>
#include <hip/hip_bf16.h>
#include <math.h>

#define B_ROWS 4096
#define D_DIM  256
#define N_TOT  8192            // 2B
#define E2     7.38905609893065f   // exp(2) = diagonal term of the row sum
#define NTILE  64              // 8192 / 128
#define NBLK   (NTILE * (NTILE + 1) / 2)   // 2080 upper-triangle tile pairs

typedef __attribute__((ext_vector_type(4))) float f32x4;
typedef __attribute__((ext_vector_type(8))) short bf16x8;   // 8 bf16, 4 VGPRs

__device__ __forceinline__ void async_copy16(const void* gptr, void* lptr) {
    // NOTE: lptr is the WAVE-UNIFORM base; HW scatters lane*16 itself.
    __builtin_amdgcn_global_load_lds(
        (const __attribute__((address_space(1))) unsigned int*)gptr,
        (__attribute__((address_space(3))) unsigned int*)lptr,
        16 /*bytes*/, 0 /*offset*/, 0 /*aux*/);
}

__device__ __forceinline__ void decode_tri(int bid, int& bi, int& bj) {
    int b = 0, rowStart = 0;
    while (rowStart + (NTILE - b) <= bid) { rowStart += NTILE - b; ++b; }
    bi = b; bj = b + (bid - rowStart);
}

// ---------------------------------------------------------------------------
// Kernel 1: L2-normalize q,p -> bf16 Z[8192][256] (wave per row, 4 rows per
// block); pospart[row] = zq.zp (fp32-exact); zero denom; reset counter.
// bf16 (not fp8): the fp8 GEMM regressed 45->164us unexplained (R7) --
// quarantined until disasm evidence explains it.
// ---------------------------------------------------------------------------
__global__ __launch_bounds__(256) void norm_kernel(
        const float* __restrict__ q, const float* __restrict__ p,
        __hip_bfloat16* __restrict__ Z, float* __restrict__ pospart,
        float* __restrict__ denom, unsigned int* __restrict__ counter) {
    const int tid  = threadIdx.x;
    const int lane = tid & 63;
    const int row  = blockIdx.x * 4 + (tid >> 6);
    if (blockIdx.x < 32) denom[blockIdx.x * 256 + tid] = 0.0f;
    if (blockIdx.x == 0 && tid == 0) *counter = 0u;

    const f32x4 q4 = *(const f32x4*)(q + (size_t)row * D_DIM + lane * 4);
    const f32x4 p4 = *(const f32x4*)(p + (size_t)row * D_DIM + lane * 4);
    float a = q4[0]*q4[0] + q4[1]*q4[1] + q4[2]*q4[2] + q4[3]*q4[3];
    float b = p4[0]*p4[0] + p4[1]*p4[1] + p4[2]*p4[2] + p4[3]*p4[3];
    float c = q4[0]*p4[0] + q4[1]*p4[1] + q4[2]*p4[2] + q4[3]*p4[3];
    #pragma unroll
    for (int off = 1; off < 64; off <<= 1) {   // butterfly: all lanes get sums
        a += __shfl_xor(a, off);
        b += __shfl_xor(b, off);
        c += __shfl_xor(c, off);
    }
    const float rq = 1.0f / fmaxf(sqrtf(a), 1e-12f);
    const float rp = 1.0f / fmaxf(sqrtf(b), 1e-12f);

    short4 zq, zp;
    zq.x = __bfloat16_as_short(__float2bfloat16(q4[0] * rq));
    zq.y = __bfloat16_as_short(__float2bfloat16(q4[1] * rq));
    zq.z = __bfloat16_as_short(__float2bfloat16(q4[2] * rq));
    zq.w = __bfloat16_as_short(__float2bfloat16(q4[3] * rq));
    zp.x = __bfloat16_as_short(__float2bfloat16(p4[0] * rp));
    zp.y = __bfloat16_as_short(__float2bfloat16(p4[1] * rp));
    zp.z = __bfloat16_as_short(__float2bfloat16(p4[2] * rp));
    zp.w = __bfloat16_as_short(__float2bfloat16(p4[3] * rp));
    ((short4*)(Z + (size_t)row * D_DIM))[lane]            = zq;
    ((short4*)(Z + (size_t)(B_ROWS + row) * D_DIM))[lane] = zp;
    if (lane == 0) pospart[row] = c * rq * rp;
}

// ---------------------------------------------------------------------------
// Kernel 2: one 128x128 tile pair of S = Z*Z^T (bf16) per block, upper
// triangle only (symmetry): epilogue exp(2s) row sums + (off-diag) col sums
// atomicAdd'ed into denom[8192]. EXACT R3 body (measured 45.5us, MfmaUtil
// 13.9%, conflicts 0): BK=64 (4 K-iters), 16+16 KB LDS, XOR swizzle on the
// global source side, ds_read_b128 fragments, launch_bounds(256,3) -- the
// verified no-spill regime ((256,5) spilled 100 MB scratch in R4).
// Last block to finish folds in the final reduction (saves a dispatch; the
// coop grid.sync alternative cost ~250us idle spin in R6).
// ---------------------------------------------------------------------------
__global__ __launch_bounds__(256, 3) void gemm_fin(
        const __hip_bfloat16* __restrict__ Z, float* __restrict__ denom,
        const float* __restrict__ pospart, unsigned int* __restrict__ counter,
        float* __restrict__ out) {
    __shared__ __hip_bfloat16 As[128 * 64];   // 16 KB, row stride 128 B
    __shared__ __hip_bfloat16 Bs[128 * 64];   // 16 KB
    const int tid    = threadIdx.x;
    const int lane   = tid & 63;
    const int wv     = tid >> 6;      // wave id 0..3
    const int wave_m = wv >> 1;       // 0..1  (row half)
    const int wave_n = wv & 1;        // 0..1  (col half)
    const int m16    = lane & 15;
    const int quad   = lane >> 4;
    const int lrow   = lane >> 3;     // staging: local row in 8-row group
    const int lchk   = lane & 7;      // 16B chunk slot

    int bi, bj;
    decode_tri(blockIdx.x, bi, bj);
    const int rowBase = bi * 128;
    const int colBase = bj * 128;

    f32x4 acc[4][4];
    #pragma unroll
    for (int i = 0; i < 4; ++i)
        #pragma unroll
        for (int j = 0; j < 4; ++j) acc[i][j] = (f32x4){0.f, 0.f, 0.f, 0.f};

    for (int kt = 0; kt < 4; ++kt) {
        const int k0 = kt * 64;            // element offset in K
        __syncthreads();   // prev iter's LDS reads done before overwrite
        #pragma unroll
        for (int pp = 0; pp < 4; ++pp) {
            const int r = wv * 32 + pp * 8 + lrow;   // local row 0..127
            const int g = lchk ^ (r & 7);            // swizzled 16B chunk
            async_copy16(Z + (size_t)(rowBase + r) * D_DIM + k0 + g * 8,
                         (char*)As + (wv * 32 + pp * 8) * 128);
            async_copy16(Z + (size_t)(colBase + r) * D_DIM + k0 + g * 8,
                         (char*)Bs + (wv * 32 + pp * 8) * 128);
        }
        __syncthreads();   // drains vmcnt: staging complete

        #pragma unroll
        for (int kt2 = 0; kt2 < 2; ++kt2) {
            const int sw = (kt2 * 4 + quad) ^ (m16 & 7);  // swizzled chunk
            bf16x8 af[4], bfr[4];
            #pragma unroll
            for (int mi = 0; mi < 4; ++mi) {
                const int r = wave_m * 64 + mi * 16 + m16;
                af[mi] = *(const bf16x8*)((const char*)As + r * 128 + sw * 16);
            }
            #pragma unroll
            for (int ni = 0; ni < 4; ++ni) {
                const int r = wave_n * 64 + ni * 16 + m16;
                bfr[ni] = *(const bf16x8*)((const char*)Bs + r * 128 + sw * 16);
            }
            #pragma unroll
            for (int mi = 0; mi < 4; ++mi)
                #pragma unroll
                for (int ni = 0; ni < 4; ++ni)
                    acc[mi][ni] = __builtin_amdgcn_mfma_f32_16x16x32_bf16(
                        af[mi], bfr[ni], acc[mi][ni], 0, 0, 0);
        }
    }

    // epilogue: exp(2s); row partials + (off-diag) col partials.
    // C/D layout: col = lane&15, row = quad*4 + reg  [m89-verified]
    float cs[4] = {0.f, 0.f, 0.f, 0.f};
    float rs[4][4];
    #pragma unroll
    for (int mi = 0; mi < 4; ++mi)
        #pragma unroll
        for (int r = 0; r < 4; ++r) {
            float s = 0.f;
            #pragma unroll
            for (int ni = 0; ni < 4; ++ni) {
                const float e = __expf(2.0f * acc[mi][ni][r]);
                s += e;
                cs[ni] += e;
            }
            rs[mi][r] = s;
        }
    #pragma unroll
    for (int off = 1; off < 16; off <<= 1)
        #pragma unroll
        for (int mi = 0; mi < 4; ++mi)
            #pragma unroll
            for (int r = 0; r < 4; ++r)
                rs[mi][r] += __shfl_xor(rs[mi][r], off, 64);
    if (m16 == 0) {
        #pragma unroll
        for (int mi = 0; mi < 4; ++mi)
            #pragma unroll
            for (int r = 0; r < 4; ++r)
                atomicAdd(&denom[rowBase + wave_m * 64 + mi * 16 + quad * 4 + r],
                          rs[mi][r]);
    }
    if (bi != bj) {
        #pragma unroll
        for (int off = 16; off < 64; off <<= 1)
            #pragma unroll
            for (int ni = 0; ni < 4; ++ni)
                cs[ni] += __shfl_xor(cs[ni], off, 64);
        if (lane < 16) {
            #pragma unroll
            for (int ni = 0; ni < 4; ++ni)
                atomicAdd(&denom[colBase + wave_n * 64 + ni * 16 + m16], cs[ni]);
        }
    }

    // ---- last block to finish performs the final reduction ----
    __threadfence();
    __shared__ int lastflag;
    if (tid == 0) lastflag = (atomicAdd(counter, 1u) == NBLK - 1) ? 1 : 0;
    __syncthreads();
    if (lastflag) {
        // denom read via atomicAdd(+0) -> read at the coherent point, safe
        // across XCDs regardless of which L2 holds the line.
        float s = 0.f;
        #pragma unroll
        for (int i = 0; i < N_TOT / 256; ++i)
            s += logf(atomicAdd(&denom[i * 256 + tid], 0.0f) - E2);
        float pp = 0.f;
        #pragma unroll
        for (int i = 0; i < B_ROWS / 256; ++i) pp += pospart[i * 256 + tid];
        s -= 4.0f * pp;
        #pragma unroll
        for (int off = 32; off > 0; off >>= 1) s += __shfl_down(s, off);
        __shared__ float red[4];
        if ((tid & 63) == 0) red[tid >> 6] = s;
        __syncthreads();
        if (tid == 0)
            out[0] = (red[0] + red[1] + red[2] + red[3]) / (float)N_TOT;
    }
}

extern "C" void kernel_launch(void* const* d_in, const int* in_sizes, int n_in,
                              void* d_out, int out_size, void* d_ws, size_t ws_size,
                              hipStream_t stream) {
    const float* q = (const float*)d_in[0];
    const float* p = (const float*)d_in[1];
    // d_in[2] (neg) is normalized in the original but never used in the loss.
    float* out = (float*)d_out;

    // Workspace: Z bf16 [8192*256] (4 MiB) | denom f32 [8192] | pospart f32
    // [4096] | done-counter u32
    __hip_bfloat16* Z = (__hip_bfloat16*)d_ws;
    float* denom   = (float*)((char*)d_ws + (size_t)N_TOT * D_DIM * sizeof(__hip_bfloat16));
    float* pospart = denom + N_TOT;
    unsigned int* counter = (unsigned int*)(pospart + B_ROWS);

    hipLaunchKernelGGL(norm_kernel, dim3(B_ROWS / 4), dim3(256), 0, stream,
                       q, p, Z, pospart, denom, counter);
    hipLaunchKernelGGL(gemm_fin, dim3(NBLK), dim3(256), 0, stream,
                       Z, denom, pospart, counter, out);
}